// Round 10
// baseline (263.749 us; speedup 1.0000x reference)
//
#include <hip/hip_runtime.h>

typedef __bf16 bf16;
typedef __bf16 bf16x4 __attribute__((ext_vector_type(4)));
typedef __bf16 bf16x8 __attribute__((ext_vector_type(8)));
typedef float f32x4 __attribute__((ext_vector_type(4)));

#define T_SEQ 2048
#define QK_LD 2048

extern "C" __device__ float __ocml_native_exp2_f32(float);   // raw v_exp_f32

__device__ inline uint4 pack8(float4 a, float4 b) {
    bf16x8 v;
    v[0] = (bf16)a.x; v[1] = (bf16)a.y; v[2] = (bf16)a.z; v[3] = (bf16)a.w;
    v[4] = (bf16)b.x; v[5] = (bf16)b.y; v[6] = (bf16)b.z; v[7] = (bf16)b.w;
    return __builtin_bit_cast(uint4, v);
}

// ---------------------------------------------------------------------------
// Fused transpose+cvt for BOTH weights (one dispatch):
//   x-blocks [0,96)  : W_qkv (1024x3072) -> wtq (3072x1024)
//   x-blocks [96,128): W_out (1024x1024) -> wto (1024x1024)
// ---------------------------------------------------------------------------
__global__ void transpose_cvt2(const float* __restrict__ Wq, bf16* __restrict__ Wtq,
                               const float* __restrict__ Wo, bf16* __restrict__ Wto) {
    __shared__ float tile[32][33];
    const bool isQ = blockIdx.x < 96;
    const float* W = isQ ? Wq : Wo;
    bf16* Wt = isQ ? Wtq : Wto;
    const int C = isQ ? 3072 : 1024;
    const int R = 1024;
    const int bx = (isQ ? blockIdx.x : (blockIdx.x - 96)) * 32;
    const int by = blockIdx.y * 32;
    const int tx = threadIdx.x, ty = threadIdx.y;
#pragma unroll
    for (int i = 0; i < 32; i += 8)
        tile[ty + i][tx] = W[(size_t)(by + ty + i) * C + bx + tx];
    __syncthreads();
#pragma unroll
    for (int i = 0; i < 32; i += 8)
        Wt[(size_t)(bx + ty + i) * R + by + tx] = (bf16)tile[tx][ty + i];
}

// ---------------------------------------------------------------------------
// GEMM: C[M,N] = A[M,K]*Bt[N,K]^T (+bias). fp32 acc.  [r6-validated core]
// Block tile (32*MT) x 128, BK=32, 256 thr; wave tile (16*MT) x 64.
//   MT=4: 128x128 (QKV shape, measured 27.9% MfmaUtil, conflicts 0)
//   MT=2:  64x128 (out-proj: 1024 blocks -> fills 768 slots better than 512)
// A_F32: A consumed in fp32, converted to bf16 in the register-staging path
// (kills the separate cvt kernel). Global loads stay row-contiguous per wave
// (r8 lesson: fragment-shaped global access serializes in the TA).
// Register staging with statically-named sets (dynamic indexing spills: r5).
// Coalesced rows in -> XOR-swizzled LDS chunks out; ds_read_b128 conflict-free.
// Distance-2 prefetch, single barrier per phase.
// ---------------------------------------------------------------------------
template <bool OUT_BF16, bool SPLIT_V, bool A_F32, int MT>
__global__ __launch_bounds__(256, 3)
void gemm_bt(const void* __restrict__ Av, const bf16* __restrict__ Bt,
             const float* __restrict__ bias, void* __restrict__ Cout,
             bf16* __restrict__ Vtb, int M, int N, int K, int ldC) {
    constexpr int AE  = 1024 * MT;     // A elems per buf
    constexpr int BUF = AE + 4096;     // buf stride (elems)
    __shared__ bf16 sm[2 * BUF];

    const int t = threadIdx.x;
    const int lane = t & 63, quad = lane >> 4, l16 = lane & 15;
    const int wave = t >> 6;
    const int wm = (wave >> 1) * (16 * MT);
    const int wn = (wave & 1) * 64;
    const long m0 = (long)blockIdx.y * (32 * MT);
    const long n0 = (long)blockIdx.x * 128;

    f32x4 acc[MT][4] = {};

    const int sr = t >> 2, sc = t & 3;
    const int swzA  = (sr * 4 + (sc ^ ((sr >> 1) & 3))) * 8;          // row sr
    const int swzA2 = ((sr + 64) * 4 + (sc ^ ((sr >> 1) & 3))) * 8;   // row sr+64
    const bf16*  agph = (const bf16*)Av  + (m0 + sr) * (long)K + sc * 8;
    const float* agpf = (const float*)Av + (m0 + sr) * (long)K + sc * 8;
    const bf16* bgp = Bt + (n0 + sr) * (long)K + sc * 8;
    const long rowK = (long)64 * K;

    int offA[MT], offB[4];
#pragma unroll
    for (int i = 0; i < MT; ++i) {
        const int row = wm + i * 16 + l16;
        offA[i] = (row * 4 + (quad ^ ((row >> 1) & 3))) * 8;
    }
#pragma unroll
    for (int j = 0; j < 4; ++j) {
        const int row = wn + j * 16 + l16;
        offB[j] = AE + (row * 4 + (quad ^ ((row >> 1) & 3))) * 8;
    }

    // statically-named staging sets (VGPR-resident)
    uint4 s0a0, s0a1, s0b0, s0b1;
    uint4 s1a0, s1a1, s1b0, s1b1;

    auto load0 = [&](int k) {
        if constexpr (A_F32) {
            s0a0 = pack8(*(const float4*)(agpf + k), *(const float4*)(agpf + k + 4));
            if constexpr (MT == 4)
                s0a1 = pack8(*(const float4*)(agpf + rowK + k),
                             *(const float4*)(agpf + rowK + k + 4));
        } else {
            s0a0 = *(const uint4*)(agph + k);
            if constexpr (MT == 4) s0a1 = *(const uint4*)(agph + rowK + k);
        }
        s0b0 = *(const uint4*)(bgp + k);
        s0b1 = *(const uint4*)(bgp + rowK + k);
    };
    auto load1 = [&](int k) {
        if constexpr (A_F32) {
            s1a0 = pack8(*(const float4*)(agpf + k), *(const float4*)(agpf + k + 4));
            if constexpr (MT == 4)
                s1a1 = pack8(*(const float4*)(agpf + rowK + k),
                             *(const float4*)(agpf + rowK + k + 4));
        } else {
            s1a0 = *(const uint4*)(agph + k);
            if constexpr (MT == 4) s1a1 = *(const uint4*)(agph + rowK + k);
        }
        s1b0 = *(const uint4*)(bgp + k);
        s1b1 = *(const uint4*)(bgp + rowK + k);
    };
    auto write0 = [&]() {   // always buf0
        *(uint4*)(sm + swzA) = s0a0;
        if constexpr (MT == 4) *(uint4*)(sm + swzA2) = s0a1;
        *(uint4*)(sm + AE + swzA)  = s0b0;
        *(uint4*)(sm + AE + swzA2) = s0b1;
    };
    auto write1 = [&]() {   // always buf1
        bf16* base = sm + BUF;
        *(uint4*)(base + swzA) = s1a0;
        if constexpr (MT == 4) *(uint4*)(base + swzA2) = s1a1;
        *(uint4*)(base + AE + swzA)  = s1b0;
        *(uint4*)(base + AE + swzA2) = s1b1;
    };
    auto compute = [&](const bf16* s) {
        bf16x8 af[MT], bfr[4];
#pragma unroll
        for (int i = 0; i < MT; ++i) af[i] = *(const bf16x8*)(s + offA[i]);
#pragma unroll
        for (int j = 0; j < 4; ++j) bfr[j] = *(const bf16x8*)(s + offB[j]);
#pragma unroll
        for (int i = 0; i < MT; ++i)
#pragma unroll
            for (int j = 0; j < 4; ++j)   // swapped: D row=n, col=m
                acc[i][j] = __builtin_amdgcn_mfma_f32_16x16x32_bf16(bfr[j], af[i], acc[i][j], 0, 0, 0);
    };

    const int nk = K >> 5;
    load0(0);
    load1(32);
    write0();
    load0(64);
    __syncthreads();

    for (int kk = 0; kk < nk; kk += 2) {
        if (kk + 1 < nk) {
            write1();
            if (kk + 3 < nk) load1((kk + 3) * 32);
        }
        compute(sm);
        if (kk + 1 < nk) {
            __syncthreads();
            if (kk + 2 < nk) {
                write0();
                if (kk + 4 < nk) load0((kk + 4) * 32);
            }
            compute(sm + BUF);
            if (kk + 2 < nk) __syncthreads();
        }
    }

    // epilogue: lane holds m = m0+wm+i*16+l16, n = n0+wn+j*16+quad*4+r
    bf16*  Cb = (bf16*)Cout;
    float* Cf = (float*)Cout;
    const bool vblock = SPLIT_V && (n0 >= 2048);
#pragma unroll
    for (int i = 0; i < MT; ++i) {
        const long gm = m0 + wm + i * 16 + l16;
#pragma unroll
        for (int j = 0; j < 4; ++j) {
            const int nloc = wn + j * 16 + quad * 4;
            const long n = n0 + nloc;
            const float4 bv = *(const float4*)(bias + n);
            float v[4];
#pragma unroll
            for (int r = 0; r < 4; ++r) v[r] = acc[i][j][r] + (&bv.x)[r];
            if (vblock) {
                const int bb = (int)(gm >> 11), tok = (int)(gm & 2047);
                const int nv = (int)(n - 2048);
                const int h = nv >> 6, d0 = nv & 63;
                bf16* dst = Vtb + ((size_t)(bb * 16 + h) * 64 + d0) * T_SEQ + tok;
#pragma unroll
                for (int r = 0; r < 4; ++r) dst[(size_t)r * T_SEQ] = (bf16)v[r];
            } else if (OUT_BF16) {
                bf16x4 o;
#pragma unroll
                for (int r = 0; r < 4; ++r) o[r] = (bf16)v[r];
                *(bf16x4*)(Cb + gm * ldC + n) = o;
            } else {
                float4 o;
#pragma unroll
                for (int r = 0; r < 4; ++r) (&o.x)[r] = v[r];
                *(float4*)(Cf + gm * ldC + n) = o;
            }
        }
    }
}

// ---------------------------------------------------------------------------
// Causal flash attention  [r6/r9 verbatim — best measured ~75 us].
// Transposed orientation; K/V staged to swizzled LDS from coalesced-row
// register prefetch; single barrier per k-tile (dbuf); wave-private P
// round-trip; fixed-max exp2 softmax.
// ---------------------------------------------------------------------------
__global__ __launch_bounds__(256, 3)
void attn_kernel(const bf16* __restrict__ qk, const bf16* __restrict__ vtb,
                 bf16* __restrict__ Out) {
    const int bh = blockIdx.x;
    const int qt = 15 - (int)blockIdx.y;    // heavy tiles first
    const int b = bh >> 4, h = bh & 15;
    const int t = threadIdx.x;
    const int wave = t >> 6, lane = t & 63, quad = lane >> 4, l16 = lane & 15;
    const int wq = wave * 32;
    const int q0 = qt * 128;

    __shared__ bf16 Ks[2][4096];
    __shared__ bf16 VTs[2][4096];
    __shared__ bf16 Ps[8192];

    const bf16* Qg = qk + (size_t)b * T_SEQ * QK_LD + h * 64;
    const bf16* Kg = Qg + 1024;
    const bf16* vth = vtb + (size_t)bh * 64 * T_SEQ;

    for (int c = t; c < 1024; c += 256) {
        const int row = c >> 3, kb = c & 7;
        *(uint4*)(Ps + row * 64 + (((kb ^ (row & 7)) << 3))) =
            *(const uint4*)(Qg + (size_t)(q0 + row) * QK_LD + kb * 8);
    }
    __syncthreads();
    const float qsc = 0.125f * 1.4426950408889634f;
    bf16x8 qf[2][2];
#pragma unroll
    for (int jt = 0; jt < 2; ++jt)
#pragma unroll
        for (int s = 0; s < 2; ++s) {
            const int row = wq + jt * 16 + l16;
            bf16x8 v = *(const bf16x8*)(Ps + row * 64 + (((s * 4 + quad) ^ (row & 7)) << 3));
#pragma unroll
            for (int e = 0; e < 8; ++e) v[e] = (bf16)((float)v[e] * qsc);
            qf[jt][s] = v;
        }

    const int sr = t >> 3;
    const int skb = (t & 7) ^ (sr & 7);
    const bf16* kp0 = Kg + (size_t)sr * QK_LD + skb * 8;
    const bf16* kp1 = kp0 + (size_t)32 * QK_LD;
    const bf16* vp0 = vth + (size_t)sr * T_SEQ + skb * 8;
    const bf16* vp1 = vp0 + (size_t)32 * T_SEQ;

    int offKV[4][2];
#pragma unroll
    for (int it = 0; it < 4; ++it)
#pragma unroll
        for (int s = 0; s < 2; ++s) {
            const int row = it * 16 + l16;
            offKV[it][s] = row * 64 + (((s * 4 + quad) ^ (row & 7)) << 3);
        }

    f32x4 oacc[4][2] = {};
    float lsum[2] = {0.f, 0.f};
    const int nkt = qt * 2 + 2;

    uint4 kr0 = *(const uint4*)kp0, kr1 = *(const uint4*)kp1;
    uint4 vr0 = *(const uint4*)vp0, vr1 = *(const uint4*)vp1;

    for (int kt = 0; kt < nkt; ++kt) {
        const int k0 = kt * 64;
        bf16* kb_ = Ks[kt & 1];
        bf16* vb_ = VTs[kt & 1];
        *(uint4*)(kb_ + t * 8)        = kr0;
        *(uint4*)(kb_ + 2048 + t * 8) = kr1;
        *(uint4*)(vb_ + t * 8)        = vr0;
        *(uint4*)(vb_ + 2048 + t * 8) = vr1;
        __syncthreads();

        if (kt + 1 < nkt) {
            const int kn = k0 + 64;
            kr0 = *(const uint4*)(kp0 + (size_t)kn * QK_LD);
            kr1 = *(const uint4*)(kp1 + (size_t)kn * QK_LD);
            vr0 = *(const uint4*)(vp0 + kn);
            vr1 = *(const uint4*)(vp1 + kn);
        }

        f32x4 sacc[4][2] = {};
#pragma unroll
        for (int s = 0; s < 2; ++s) {
            bf16x8 kf[4];
#pragma unroll
            for (int it = 0; it < 4; ++it)
                kf[it] = *(const bf16x8*)(kb_ + offKV[it][s]);
#pragma unroll
            for (int it = 0; it < 4; ++it)
#pragma unroll
                for (int jt = 0; jt < 2; ++jt)
                    sacc[it][jt] = __builtin_amdgcn_mfma_f32_16x16x32_bf16(kf[it], qf[jt][s], sacc[it][jt], 0, 0, 0);
        }

        const bool need_mask = (kt >= 2 * qt);
#pragma unroll
        for (int it = 0; it < 4; ++it)
#pragma unroll
            for (int jt = 0; jt < 2; ++jt) {
                const int prow = wq + jt * 16 + l16;
                bf16x4 pb;
                if (need_mask) {
                    const int qrow = q0 + prow;
                    const int kbase = k0 + it * 16 + quad * 4;
#pragma unroll
                    for (int r = 0; r < 4; ++r) {
                        const float e = __ocml_native_exp2_f32(sacc[it][jt][r]);
                        const float p = (kbase + r > qrow) ? 0.f : e;
                        lsum[jt] += p;
                        pb[r] = (bf16)p;
                    }
                } else {
#pragma unroll
                    for (int r = 0; r < 4; ++r) {
                        const float p = __ocml_native_exp2_f32(sacc[it][jt][r]);
                        lsum[jt] += p;
                        pb[r] = (bf16)p;
                    }
                }
                *(bf16x4*)(Ps + prow * 64 +
                           (((it * 2 + (quad >> 1)) ^ (prow & 7)) << 3) + ((quad & 1) << 2)) = pb;
            }

#pragma unroll
        for (int s2 = 0; s2 < 2; ++s2) {
            bf16x8 vf[4], pf[2];
#pragma unroll
            for (int it2 = 0; it2 < 4; ++it2)
                vf[it2] = *(const bf16x8*)(vb_ + offKV[it2][s2]);
#pragma unroll
            for (int jt = 0; jt < 2; ++jt) {
                const int prow = wq + jt * 16 + l16;
                pf[jt] = *(const bf16x8*)(Ps + prow * 64 + (((s2 * 4 + quad) ^ (prow & 7)) << 3));
            }
#pragma unroll
            for (int it2 = 0; it2 < 4; ++it2)
#pragma unroll
                for (int jt = 0; jt < 2; ++jt)
                    oacc[it2][jt] = __builtin_amdgcn_mfma_f32_16x16x32_bf16(vf[it2], pf[jt], oacc[it2][jt], 0, 0, 0);
        }
    }

    float inv[2];
#pragma unroll
    for (int jt = 0; jt < 2; ++jt) {
        float l = lsum[jt];
        l += __shfl_xor(l, 16);
        l += __shfl_xor(l, 32);
        inv[jt] = 1.0f / l;
    }
#pragma unroll
    for (int it2 = 0; it2 < 4; ++it2)
#pragma unroll
        for (int jt = 0; jt < 2; ++jt) {
            bf16x4 ob;
#pragma unroll
            for (int r = 0; r < 4; ++r) ob[r] = (bf16)(oacc[it2][jt][r] * inv[jt]);
            const int qrow = q0 + wq + jt * 16 + l16;
            const int dcol = h * 64 + it2 * 16 + quad * 4;
            *(bf16x4*)&Out[(size_t)(b * T_SEQ + qrow) * 1024 + dcol] = ob;
        }
}

// ---------------------------------------------------------------------------
extern "C" void kernel_launch(void* const* d_in, const int* in_sizes, int n_in,
                              void* d_out, int out_size, void* d_ws, size_t ws_size,
                              hipStream_t stream) {
    const float* x     = (const float*)d_in[0];
    const float* W_qkv = (const float*)d_in[1];
    const float* b_qkv = (const float*)d_in[2];
    const float* W_out = (const float*)d_in[3];
    const float* b_out = (const float*)d_in[4];
    float* out = (float*)d_out;

    char* ws = (char*)d_ws;
    bf16* wtq  = (bf16*)ws; ws += (size_t)3072 * 1024 * 2;
    bf16* wto  = (bf16*)ws; ws += (size_t)1024 * 1024 * 2;
    bf16* qkb  = (bf16*)ws; ws += (size_t)8192 * 2048 * 2;    // Q|K rows
    bf16* vtb  = (bf16*)ws; ws += (size_t)64 * 64 * 2048 * 2; // V^T per bh
    bf16* aout = (bf16*)ws; ws += (size_t)8192 * 1024 * 2;

    transpose_cvt2<<<dim3(128, 32), dim3(32, 8), 0, stream>>>(W_qkv, wtq, W_out, wto);

    // QKV GEMM consumes x in fp32 directly (cvt fused into register staging)
    gemm_bt<true, true, true, 4><<<dim3(24, 64), 256, 0, stream>>>(
        x, wtq, b_qkv, (void*)qkb, vtb, 8192, 3072, 1024, 2048);
    attn_kernel<<<dim3(64, 16), 256, 0, stream>>>(qkb, vtb, aout);
    // out-proj: 64x128 tile (MT=2) -> 1024 blocks, better CU-slot fill
    gemm_bt<false, false, false, 2><<<dim3(8, 128), 256, 0, stream>>>(
        aout, wto, b_out, (void*)out, nullptr, 8192, 1024, 1024, 1024);
}

// Round 11
// 241.160 us; speedup vs baseline: 1.0937x; 1.0937x over previous
//
#include <hip/hip_runtime.h>

typedef __bf16 bf16;
typedef __bf16 bf16x4 __attribute__((ext_vector_type(4)));
typedef __bf16 bf16x8 __attribute__((ext_vector_type(8)));
typedef float f32x4 __attribute__((ext_vector_type(4)));

#define T_SEQ 2048
#define QK_LD 2048

extern "C" __device__ float __ocml_native_exp2_f32(float);   // raw v_exp_f32

// ---------------------------------------------------------------------------
// Fused prep (one dispatch, 256-thr blocks):
//   blocks [0, 8192)        : x (fp32, 8192x1024) -> xb bf16
//   blocks [8192, 8192+3072): W_qkv (1024x3072) -> wtq (3072x1024) bf16
//   blocks [+3072, +4096)   : W_out (1024x1024) -> wto (1024x1024) bf16
// ---------------------------------------------------------------------------
__global__ void prep_kernel(const float* __restrict__ x, bf16* __restrict__ xb,
                            const float* __restrict__ Wq, bf16* __restrict__ Wtq,
                            const float* __restrict__ Wo, bf16* __restrict__ Wto) {
    __shared__ float tile[32][33];
    const int t = threadIdx.x;
    if (blockIdx.x < 8192) {
        const int i = (blockIdx.x * 256 + t) * 4;
        const float4 f = *(const float4*)(x + i);
        bf16x4 o;
        o.x = (bf16)f.x; o.y = (bf16)f.y; o.z = (bf16)f.z; o.w = (bf16)f.w;
        *(bf16x4*)(xb + i) = o;
        return;
    }
    const int bid = blockIdx.x - 8192;            // [0, 4096)
    const int xblk = bid & 127, yblk = bid >> 7;  // 128 x 32 tiles of 32x32
    const bool isQ = xblk < 96;
    const float* W = isQ ? Wq : Wo;
    bf16* Wt = isQ ? Wtq : Wto;
    const int C = isQ ? 3072 : 1024;
    const int R = 1024;
    const int bx = (isQ ? xblk : (xblk - 96)) * 32;
    const int by = yblk * 32;
    const int tx = t & 31, ty = t >> 5;
#pragma unroll
    for (int i = 0; i < 32; i += 8)
        tile[ty + i][tx] = W[(size_t)(by + ty + i) * C + bx + tx];
    __syncthreads();
#pragma unroll
    for (int i = 0; i < 32; i += 8)
        Wt[(size_t)(bx + ty + i) * R + by + tx] = (bf16)tile[tx][ty + i];
}

// ---------------------------------------------------------------------------
// GEMM: C[M,N] = A[M,K]*Bt[N,K]^T (+bias). bf16 in, fp32 acc.  [r6/r9 verbatim]
// 128x128 tile, BK=32, 256 thr. Register staging (global->VGPR->ds_write)
// with two STATICALLY-NAMED register sets (dynamic indexing spills: r5).
// Coalesced global rows in -> XOR-swizzled LDS chunks out; frag ds_read_b128
// conflict-free. Distance-2 prefetch, single barrier per phase.
// Measured: 76-79 us on QKV shape, MfmaUtil ~27.9%, conflicts 0.
// r8 lesson: fragment-shaped direct-global loads serialize in the TA —
// fragments must come from LDS; global access stays row-contiguous per wave.
// r10 lesson: consuming A as fp32 doubles FETCH (72->137 MB) and costs 24 us
// to save a 10 us cvt — standalone cvt at HBM stream rate is cheaper.
// ---------------------------------------------------------------------------
template <bool OUT_BF16, bool SPLIT_V>
__global__ __launch_bounds__(256, 3)
void gemm_bt(const bf16* __restrict__ A, const bf16* __restrict__ Bt,
             const float* __restrict__ bias, void* __restrict__ Cout,
             bf16* __restrict__ Vtb, int M, int N, int K, int ldC) {
    __shared__ bf16 sm[16384];   // 2 bufs x (A 4096 + B 4096 elems) = 32 KB

    const int t = threadIdx.x;
    const int lane = t & 63, quad = lane >> 4, l16 = lane & 15;
    const int wave = t >> 6;
    const int wm = (wave >> 1) * 64;
    const int wn = (wave & 1) * 64;
    const long m0 = (long)blockIdx.y * 128;
    const long n0 = (long)blockIdx.x * 128;

    f32x4 acc[4][4] = {};

    const int sr = t >> 2, sc = t & 3;
    const int swz  = (sr * 4 + (sc ^ ((sr >> 1) & 3))) * 8;
    const int swz2 = ((sr + 64) * 4 + (sc ^ ((sr >> 1) & 3))) * 8;
    const bf16* agp = A  + (m0 + sr) * (long)K + sc * 8;
    const bf16* bgp = Bt + (n0 + sr) * (long)K + sc * 8;
    const long rowK = (long)64 * K;

    int offA[4], offB[4];
#pragma unroll
    for (int i = 0; i < 4; ++i) {
        const int row = wm + i * 16 + l16;
        offA[i] = (row * 4 + (quad ^ ((row >> 1) & 3))) * 8;
    }
#pragma unroll
    for (int j = 0; j < 4; ++j) {
        const int row = wn + j * 16 + l16;
        offB[j] = 4096 + (row * 4 + (quad ^ ((row >> 1) & 3))) * 8;
    }

    uint4 s0a0, s0a1, s0b0, s0b1;
    uint4 s1a0, s1a1, s1b0, s1b1;

    auto load0 = [&](int k) {
        s0a0 = *(const uint4*)(agp + k);        s0a1 = *(const uint4*)(agp + rowK + k);
        s0b0 = *(const uint4*)(bgp + k);        s0b1 = *(const uint4*)(bgp + rowK + k);
    };
    auto load1 = [&](int k) {
        s1a0 = *(const uint4*)(agp + k);        s1a1 = *(const uint4*)(agp + rowK + k);
        s1b0 = *(const uint4*)(bgp + k);        s1b1 = *(const uint4*)(bgp + rowK + k);
    };
    auto write0 = [&]() {   // always buf0
        *(uint4*)(sm + swz)         = s0a0;  *(uint4*)(sm + swz2)        = s0a1;
        *(uint4*)(sm + 4096 + swz)  = s0b0;  *(uint4*)(sm + 4096 + swz2) = s0b1;
    };
    auto write1 = [&]() {   // always buf1
        bf16* base = sm + 8192;
        *(uint4*)(base + swz)         = s1a0;  *(uint4*)(base + swz2)        = s1a1;
        *(uint4*)(base + 4096 + swz)  = s1b0;  *(uint4*)(base + 4096 + swz2) = s1b1;
    };
    auto compute = [&](const bf16* s) {
        bf16x8 af[4], bfr[4];
#pragma unroll
        for (int i = 0; i < 4; ++i) af[i] = *(const bf16x8*)(s + offA[i]);
#pragma unroll
        for (int j = 0; j < 4; ++j) bfr[j] = *(const bf16x8*)(s + offB[j]);
#pragma unroll
        for (int i = 0; i < 4; ++i)
#pragma unroll
            for (int j = 0; j < 4; ++j)   // swapped: D row=n, col=m
                acc[i][j] = __builtin_amdgcn_mfma_f32_16x16x32_bf16(bfr[j], af[i], acc[i][j], 0, 0, 0);
    };

    const int nk = K >> 5;
    load0(0);
    load1(32);
    write0();
    load0(64);
    __syncthreads();

    for (int kk = 0; kk < nk; kk += 2) {
        if (kk + 1 < nk) {
            write1();
            if (kk + 3 < nk) load1((kk + 3) * 32);
        }
        compute(sm);
        if (kk + 1 < nk) {
            __syncthreads();
            if (kk + 2 < nk) {
                write0();
                if (kk + 4 < nk) load0((kk + 4) * 32);
            }
            compute(sm + 8192);
            if (kk + 2 < nk) __syncthreads();
        }
    }

    bf16*  Cb = (bf16*)Cout;
    float* Cf = (float*)Cout;
    const bool vblock = SPLIT_V && (n0 >= 2048);
#pragma unroll
    for (int i = 0; i < 4; ++i) {
        const long gm = m0 + wm + i * 16 + l16;
#pragma unroll
        for (int j = 0; j < 4; ++j) {
            const int nloc = wn + j * 16 + quad * 4;
            const long n = n0 + nloc;
            const float4 bv = *(const float4*)(bias + n);
            float v[4];
#pragma unroll
            for (int r = 0; r < 4; ++r) v[r] = acc[i][j][r] + (&bv.x)[r];
            if (vblock) {
                const int bb = (int)(gm >> 11), tok = (int)(gm & 2047);
                const int nv = (int)(n - 2048);
                const int h = nv >> 6, d0 = nv & 63;
                bf16* dst = Vtb + ((size_t)(bb * 16 + h) * 64 + d0) * T_SEQ + tok;
#pragma unroll
                for (int r = 0; r < 4; ++r) dst[(size_t)r * T_SEQ] = (bf16)v[r];
            } else if (OUT_BF16) {
                bf16x4 o;
#pragma unroll
                for (int r = 0; r < 4; ++r) o[r] = (bf16)v[r];
                *(bf16x4*)(Cb + gm * ldC + n) = o;
            } else {
                float4 o;
#pragma unroll
                for (int r = 0; r < 4; ++r) (&o.x)[r] = v[r];
                *(float4*)(Cf + gm * ldC + n) = o;
            }
        }
    }
}

// ---------------------------------------------------------------------------
// Causal flash attention  [r6/r9 verbatim — best measured ~75 us].
// Transposed orientation; K/V staged to swizzled LDS from coalesced-row
// register prefetch; single barrier per k-tile (dbuf); wave-private P
// round-trip; fixed-max exp2 softmax.
// ---------------------------------------------------------------------------
__global__ __launch_bounds__(256, 3)
void attn_kernel(const bf16* __restrict__ qk, const bf16* __restrict__ vtb,
                 bf16* __restrict__ Out) {
    const int bh = blockIdx.x;
    const int qt = 15 - (int)blockIdx.y;    // heavy tiles first
    const int b = bh >> 4, h = bh & 15;
    const int t = threadIdx.x;
    const int wave = t >> 6, lane = t & 63, quad = lane >> 4, l16 = lane & 15;
    const int wq = wave * 32;
    const int q0 = qt * 128;

    __shared__ bf16 Ks[2][4096];
    __shared__ bf16 VTs[2][4096];
    __shared__ bf16 Ps[8192];

    const bf16* Qg = qk + (size_t)b * T_SEQ * QK_LD + h * 64;
    const bf16* Kg = Qg + 1024;
    const bf16* vth = vtb + (size_t)bh * 64 * T_SEQ;

    for (int c = t; c < 1024; c += 256) {
        const int row = c >> 3, kb = c & 7;
        *(uint4*)(Ps + row * 64 + (((kb ^ (row & 7)) << 3))) =
            *(const uint4*)(Qg + (size_t)(q0 + row) * QK_LD + kb * 8);
    }
    __syncthreads();
    const float qsc = 0.125f * 1.4426950408889634f;
    bf16x8 qf[2][2];
#pragma unroll
    for (int jt = 0; jt < 2; ++jt)
#pragma unroll
        for (int s = 0; s < 2; ++s) {
            const int row = wq + jt * 16 + l16;
            bf16x8 v = *(const bf16x8*)(Ps + row * 64 + (((s * 4 + quad) ^ (row & 7)) << 3));
#pragma unroll
            for (int e = 0; e < 8; ++e) v[e] = (bf16)((float)v[e] * qsc);
            qf[jt][s] = v;
        }

    const int sr = t >> 3;
    const int skb = (t & 7) ^ (sr & 7);
    const bf16* kp0 = Kg + (size_t)sr * QK_LD + skb * 8;
    const bf16* kp1 = kp0 + (size_t)32 * QK_LD;
    const bf16* vp0 = vth + (size_t)sr * T_SEQ + skb * 8;
    const bf16* vp1 = vp0 + (size_t)32 * T_SEQ;

    int offKV[4][2];
#pragma unroll
    for (int it = 0; it < 4; ++it)
#pragma unroll
        for (int s = 0; s < 2; ++s) {
            const int row = it * 16 + l16;
            offKV[it][s] = row * 64 + (((s * 4 + quad) ^ (row & 7)) << 3);
        }

    f32x4 oacc[4][2] = {};
    float lsum[2] = {0.f, 0.f};
    const int nkt = qt * 2 + 2;

    uint4 kr0 = *(const uint4*)kp0, kr1 = *(const uint4*)kp1;
    uint4 vr0 = *(const uint4*)vp0, vr1 = *(const uint4*)vp1;

    for (int kt = 0; kt < nkt; ++kt) {
        const int k0 = kt * 64;
        bf16* kb_ = Ks[kt & 1];
        bf16* vb_ = VTs[kt & 1];
        *(uint4*)(kb_ + t * 8)        = kr0;
        *(uint4*)(kb_ + 2048 + t * 8) = kr1;
        *(uint4*)(vb_ + t * 8)        = vr0;
        *(uint4*)(vb_ + 2048 + t * 8) = vr1;
        __syncthreads();

        if (kt + 1 < nkt) {
            const int kn = k0 + 64;
            kr0 = *(const uint4*)(kp0 + (size_t)kn * QK_LD);
            kr1 = *(const uint4*)(kp1 + (size_t)kn * QK_LD);
            vr0 = *(const uint4*)(vp0 + kn);
            vr1 = *(const uint4*)(vp1 + kn);
        }

        f32x4 sacc[4][2] = {};
#pragma unroll
        for (int s = 0; s < 2; ++s) {
            bf16x8 kf[4];
#pragma unroll
            for (int it = 0; it < 4; ++it)
                kf[it] = *(const bf16x8*)(kb_ + offKV[it][s]);
#pragma unroll
            for (int it = 0; it < 4; ++it)
#pragma unroll
                for (int jt = 0; jt < 2; ++jt)
                    sacc[it][jt] = __builtin_amdgcn_mfma_f32_16x16x32_bf16(kf[it], qf[jt][s], sacc[it][jt], 0, 0, 0);
        }

        const bool need_mask = (kt >= 2 * qt);
#pragma unroll
        for (int it = 0; it < 4; ++it)
#pragma unroll
            for (int jt = 0; jt < 2; ++jt) {
                const int prow = wq + jt * 16 + l16;
                bf16x4 pb;
                if (need_mask) {
                    const int qrow = q0 + prow;
                    const int kbase = k0 + it * 16 + quad * 4;
#pragma unroll
                    for (int r = 0; r < 4; ++r) {
                        const float e = __ocml_native_exp2_f32(sacc[it][jt][r]);
                        const float p = (kbase + r > qrow) ? 0.f : e;
                        lsum[jt] += p;
                        pb[r] = (bf16)p;
                    }
                } else {
#pragma unroll
                    for (int r = 0; r < 4; ++r) {
                        const float p = __ocml_native_exp2_f32(sacc[it][jt][r]);
                        lsum[jt] += p;
                        pb[r] = (bf16)p;
                    }
                }
                *(bf16x4*)(Ps + prow * 64 +
                           (((it * 2 + (quad >> 1)) ^ (prow & 7)) << 3) + ((quad & 1) << 2)) = pb;
            }

#pragma unroll
        for (int s2 = 0; s2 < 2; ++s2) {
            bf16x8 vf[4], pf[2];
#pragma unroll
            for (int it2 = 0; it2 < 4; ++it2)
                vf[it2] = *(const bf16x8*)(vb_ + offKV[it2][s2]);
#pragma unroll
            for (int jt = 0; jt < 2; ++jt) {
                const int prow = wq + jt * 16 + l16;
                pf[jt] = *(const bf16x8*)(Ps + prow * 64 + (((s2 * 4 + quad) ^ (prow & 7)) << 3));
            }
#pragma unroll
            for (int it2 = 0; it2 < 4; ++it2)
#pragma unroll
                for (int jt = 0; jt < 2; ++jt)
                    oacc[it2][jt] = __builtin_amdgcn_mfma_f32_16x16x32_bf16(vf[it2], pf[jt], oacc[it2][jt], 0, 0, 0);
        }
    }

    float inv[2];
#pragma unroll
    for (int jt = 0; jt < 2; ++jt) {
        float l = lsum[jt];
        l += __shfl_xor(l, 16);
        l += __shfl_xor(l, 32);
        inv[jt] = 1.0f / l;
    }
#pragma unroll
    for (int it2 = 0; it2 < 4; ++it2)
#pragma unroll
        for (int jt = 0; jt < 2; ++jt) {
            bf16x4 ob;
#pragma unroll
            for (int r = 0; r < 4; ++r) ob[r] = (bf16)(oacc[it2][jt][r] * inv[jt]);
            const int qrow = q0 + wq + jt * 16 + l16;
            const int dcol = h * 64 + it2 * 16 + quad * 4;
            *(bf16x4*)&Out[(size_t)(b * T_SEQ + qrow) * 1024 + dcol] = ob;
        }
}

// ---------------------------------------------------------------------------
extern "C" void kernel_launch(void* const* d_in, const int* in_sizes, int n_in,
                              void* d_out, int out_size, void* d_ws, size_t ws_size,
                              hipStream_t stream) {
    const float* x     = (const float*)d_in[0];
    const float* W_qkv = (const float*)d_in[1];
    const float* b_qkv = (const float*)d_in[2];
    const float* W_out = (const float*)d_in[3];
    const float* b_out = (const float*)d_in[4];
    float* out = (float*)d_out;

    char* ws = (char*)d_ws;
    bf16* xb   = (bf16*)ws; ws += (size_t)8192 * 1024 * 2;
    bf16* wtq  = (bf16*)ws; ws += (size_t)3072 * 1024 * 2;
    bf16* wto  = (bf16*)ws; ws += (size_t)1024 * 1024 * 2;
    bf16* qkb  = (bf16*)ws; ws += (size_t)8192 * 2048 * 2;    // Q|K rows
    bf16* vtb  = (bf16*)ws; ws += (size_t)64 * 64 * 2048 * 2; // V^T per bh
    bf16* aout = (bf16*)ws; ws += (size_t)8192 * 1024 * 2;

    prep_kernel<<<8192 + 4096, 256, 0, stream>>>(x, xb, W_qkv, wtq, W_out, wto);

    gemm_bt<true, true><<<dim3(24, 64), 256, 0, stream>>>(
        xb, wtq, b_qkv, (void*)qkb, vtb, 8192, 3072, 1024, 2048);
    attn_kernel<<<dim3(64, 16), 256, 0, stream>>>(qkb, vtb, aout);
    gemm_bt<false, false><<<dim3(8, 64), 256, 0, stream>>>(
        aout, wto, b_out, (void*)out, nullptr, 8192, 1024, 1024, 1024);
}